// Round 1
// baseline (116.994 us; speedup 1.0000x reference)
//
#include <hip/hip_runtime.h>
#include <hip/hip_bf16.h>
#include <stdint.h>

typedef unsigned short u16;
typedef __attribute__((ext_vector_type(8))) short short8;
typedef __attribute__((ext_vector_type(4))) float f32x4;

#define NDIM 256
#define SDIM 128
#define DDIM 64
#define HDIM 32
#define PDIM 64
#define EPS 1e-5f

__device__ __forceinline__ u16 f2bf(float f) {
  union { float f; uint32_t u; } v; v.f = f;
  uint32_t r = v.u + 0x7fffu + ((v.u >> 16) & 1u);   // RNE
  return (u16)(r >> 16);
}

// ---------------- K1: LN + dual projection via MFMA ----------------
// grid 1024: block = (n = bid>>2, sq = bid&3 -> 32 s-rows). 256 thr = 4 waves.
// a_t/b_t rows PRE-SWIZZLED: element s of row c at position
// (s&64)|(((s>>3)&7)^(c&7))<<3|(s&7). Epilogue now goes through an LDS
// transpose so each thread issues ONE b128 global store (was 8 scalar u16).
__global__ __launch_bounds__(256, 4) void k_pre(
    const float* __restrict__ msa, const float* __restrict__ mask,
    const float* __restrict__ gamma, const float* __restrict__ beta,
    const float* __restrict__ Wa, const float* __restrict__ ba,
    const float* __restrict__ Wb, const float* __restrict__ bb,
    const float* __restrict__ Wo,
    u16* __restrict__ a_t, u16* __restrict__ b_t, u16* __restrict__ W_t)
{
  __shared__ u16 xs[32 * 64];        // [s][granule swizzled] 4KB X_norm bf16
  __shared__ u16 wt[64 * 64];        // [c][granule swizzled] 8KB W^T bf16
  __shared__ u16 oT[64 * 32];        // [c][s_local] 4KB output transpose
  __shared__ float psum[2][8][32];
  __shared__ float maskF[128];
  __shared__ float gbF[128];

  const int n = blockIdx.x >> 2, sq = blockIdx.x & 3;
  const int t = threadIdx.x, lane = t & 63, wv = t >> 6;
  const int l15 = lane & 15, quad = lane >> 4;

  if (t < 64) gbF[t] = gamma[t];
  else if (t < 128) gbF[t] = beta[t - 64];
  else maskF[t - 128] = mask[(t - 128) * NDIM + n];

  // LN partials: row sl (0..31), d-slice pt8 (8 floats); 8 thr share a row
  const int sl = t >> 3, pt8 = t & 7;
  float x[8];
  {
    const float* xr = msa + ((sq * 32 + sl) * NDIM + n) * DDIM + pt8 * 8;
    float sum = 0.f, sq2 = 0.f;
    #pragma unroll
    for (int i = 0; i < 2; ++i) {
      const float4 q = ((const float4*)xr)[i];
      x[4*i] = q.x; x[4*i+1] = q.y; x[4*i+2] = q.z; x[4*i+3] = q.w;
      sum += q.x + q.y + q.z + q.w;
      sq2 += q.x*q.x + q.y*q.y + q.z*q.z + q.w*q.w;
    }
    psum[0][pt8][sl] = sum;
    psum[1][pt8][sl] = sq2;
  }

  // W^T: col c = t&63, d-slice (t>>6)*16
  {
    const int c = t & 63, ds = t >> 6;
    const int c31 = c & 31;
    const float* Wsel = (c >> 5) ? Wb : Wa;
    float w[16];
    #pragma unroll
    for (int i = 0; i < 16; ++i) w[i] = Wsel[(ds * 16 + i) * HDIM + c31];
    #pragma unroll
    for (int jj = 0; jj < 2; ++jj) {
      short8 v;
      #pragma unroll
      for (int k = 0; k < 8; ++k) v[k] = (short)f2bf(w[jj * 8 + k]);
      *(short8*)&wt[c * 64 + (((ds * 2 + jj) ^ (c & 7)) << 3)] = v;
    }
  }
  __syncthreads();

  // finish LN
  {
    float s0 = 0.f, s1 = 0.f;
    #pragma unroll
    for (int q = 0; q < 8; ++q) { s0 += psum[0][q][sl]; s1 += psum[1][q][sl]; }
    const float mu = s0 * (1.f / 64.f);
    const float var = s1 * (1.f / 64.f) - mu * mu;
    const float rs = rsqrtf(var + EPS);
    short8 v;
    #pragma unroll
    for (int k = 0; k < 8; ++k) {
      const int d = pt8 * 8 + k;
      v[k] = (short)f2bf((x[k] - mu) * rs * gbF[d] + gbF[64 + d]);
    }
    *(short8*)&xs[sl * 64 + ((pt8 ^ (sl & 7)) << 3)] = v;
  }
  float m2 = maskF[lane] + maskF[64 + lane];
  #pragma unroll
  for (int m = 32; m; m >>= 1) m2 += __shfl_xor(m2, m, 64);
  const float dinv = 1.f / fmaxf(m2, 1.f);
  __syncthreads();

  // projection: D[m=c][n=s], wave wv = c-tile [wv*16,+16); s covers 32 (2 nt)
  const f32x4 fz = {0.f, 0.f, 0.f, 0.f};
  f32x4 acc[2] = {fz, fz};
  short8 af[2];
  #pragma unroll
  for (int ks = 0; ks < 2; ++ks)
    af[ks] = *(const short8*)&wt[(wv * 16 + l15) * 64 + (((ks * 4 + quad) ^ (l15 & 7)) << 3)];
  #pragma unroll
  for (int nt = 0; nt < 2; ++nt)
    #pragma unroll
    for (int ks = 0; ks < 2; ++ks) {
      const short8 bf = *(const short8*)&xs[(nt * 16 + l15) * 64 + (((ks * 4 + quad) ^ (l15 & 7)) << 3)];
      acc[nt] = __builtin_amdgcn_mfma_f32_16x16x32_bf16(af[ks], bf, acc[nt], 0, 0, 0);
    }

  // epilogue -> LDS transpose
  const float* bsel = (wv < 2) ? ba : bb;
  float bias_r[4];
  #pragma unroll
  for (int r = 0; r < 4; ++r) bias_r[r] = bsel[(wv & 1) * 16 + quad * 4 + r];
  #pragma unroll
  for (int nt = 0; nt < 2; ++nt) {
    const int s = sq * 32 + nt * 16 + l15;
    const int slcl = nt * 16 + l15;
    const float mval = maskF[s];
    const float scale = (wv < 2) ? mval * dinv : mval;
    #pragma unroll
    for (int r = 0; r < 4; ++r) {
      const int c31 = (wv & 1) * 16 + quad * 4 + r;
      const int c = ((wv < 2) ? 0 : 32) + c31;
      oT[c * 32 + slcl] = f2bf((acc[nt][r] + bias_r[r]) * scale);
    }
  }
  __syncthreads();

  // one b128 store per thread: thread -> (c = t>>2, granule gi = t&3)
  {
    const int c = t >> 2, gi = t & 3;
    const int c31 = c & 31;
    const int s0 = sq * 32 + gi * 8;
    u16* dst = ((c < 32) ? a_t : b_t) + n * 4096 + c31 * 128
             + (s0 & 64) + ((((s0 >> 3) & 7) ^ (c31 & 7)) << 3);
    *(short8*)dst = *(const short8*)&oT[c * 32 + gi * 8];
  }

  // W_t2[hk>>3][p][hk&7] = bf16(Wo[hk][p])
  if (blockIdx.x < 256) {
    const int f = blockIdx.x * 256 + t;        // f = hk*64 + p
    const int p = f & 63, hk = f >> 6;
    W_t[(hk >> 3) * 512 + p * 8 + (hk & 7)] = f2bf(Wo[f]);
  }
}

// ---------------- K2: fused outer-product GEMM + Wo contraction ----------------
// grid (32 jT, 32 iT) x 512 thr (8 waves: wi 0..3 ih-quarter, wj 0..1 jk-half).
// 128 KB dynamic LDS. NEW vs baseline: stage A is fully DOUBLE-BUFFERED —
// all 16 global_load_lds (both K-chunks) issue up front into
// As0/Bs0/As1/Bs1 (4x32KB = 128KB), then counted s_waitcnt vmcnt(8) + raw
// barrier gates chunk-0 compute while chunk-1's 8 loads stay in flight
// (T3/T4 pattern). Removes the 2x full vmcnt(0) drain + 2 barriers of the
// baseline's load->drain->compute serialization. T5 setprio around MFMA
// clusters. Gs (128KB) aliases the staging buffers only after both chunks'
// LDS reads complete (guarded by __syncthreads).
__global__ __launch_bounds__(512, 2) void k_fused(
    const u16* __restrict__ a_t, const u16* __restrict__ b_t,
    const u16* __restrict__ W_t, const float* __restrict__ bo,
    float* __restrict__ out)
{
  extern __shared__ char smem[];
  u16* As0 = (u16*)smem;                  // [256 ih][64 k] chunk0, 32KB
  u16* Bs0 = (u16*)(smem + 32768);        // [256 jk][64 k] chunk0, 32KB
  u16* As1 = (u16*)(smem + 65536);        // chunk1, 32KB
  u16* Bs1 = (u16*)(smem + 98304);        // chunk1, 32KB
  u16* Gs = (u16*)smem;                   // [64 rij][1024 hk] swizzled, 128KB
  float* red = (float*)smem;              // [4 kq][64 rij][68] f32, 69.6KB

  const int tid = threadIdx.x, lane = tid & 63, wv = tid >> 6;
  const int l15 = lane & 15, quad = lane >> 4;
  const int wi = wv >> 1, wj = wv & 1;
  const int jT = blockIdx.x, iT = blockIdx.y;

  const u16* gA = a_t + iT * 256 * SDIM;
  const u16* gB = b_t + jT * 256 * SDIM;

  const f32x4 fz = {0.f, 0.f, 0.f, 0.f};
  f32x4 acc[8][4];                   // [jt][it]
  #pragma unroll
  for (int jt = 0; jt < 8; ++jt)
    #pragma unroll
    for (int it = 0; it < 4; ++it) acc[jt][it] = fz;

  const int sub8 = lane >> 3, g16 = lane & 7;

  // ---- issue ALL staging up front: ch0 (8 glds) then ch1 (8 glds) ----
  #pragma unroll
  for (int i = 0; i < 4; ++i) {
    const int rbase = wv * 32 + i * 8;
    __builtin_amdgcn_global_load_lds(
        (const __attribute__((address_space(1))) void*)&gA[(rbase + sub8) * SDIM + g16 * 8],
        (__attribute__((address_space(3))) void*)&As0[rbase * 64], 16, 0, 0);
  }
  #pragma unroll
  for (int i = 0; i < 4; ++i) {
    const int rbase = wv * 32 + i * 8;
    __builtin_amdgcn_global_load_lds(
        (const __attribute__((address_space(1))) void*)&gB[(rbase + sub8) * SDIM + g16 * 8],
        (__attribute__((address_space(3))) void*)&Bs0[rbase * 64], 16, 0, 0);
  }
  #pragma unroll
  for (int i = 0; i < 4; ++i) {
    const int rbase = wv * 32 + i * 8;
    __builtin_amdgcn_global_load_lds(
        (const __attribute__((address_space(1))) void*)&gA[(rbase + sub8) * SDIM + 64 + g16 * 8],
        (__attribute__((address_space(3))) void*)&As1[rbase * 64], 16, 0, 0);
  }
  #pragma unroll
  for (int i = 0; i < 4; ++i) {
    const int rbase = wv * 32 + i * 8;
    __builtin_amdgcn_global_load_lds(
        (const __attribute__((address_space(1))) void*)&gB[(rbase + sub8) * SDIM + 64 + g16 * 8],
        (__attribute__((address_space(3))) void*)&Bs1[rbase * 64], 16, 0, 0);
  }

  auto compute_chunk = [&](const u16* __restrict__ Asb, const u16* __restrict__ Bsb) {
    #pragma unroll
    for (int ks = 0; ks < 2; ++ks) {
      const int g = ks * 4 + quad;
      short8 afr[4], bfr[8];
      #pragma unroll
      for (int it = 0; it < 4; ++it) {
        const int row = wi * 64 + it * 16 + l15;
        afr[it] = *(const short8*)&Asb[row * 64 + ((g ^ (row & 7)) << 3)];
      }
      #pragma unroll
      for (int jt = 0; jt < 8; ++jt) {
        const int row = wj * 128 + jt * 16 + l15;
        bfr[jt] = *(const short8*)&Bsb[row * 64 + ((g ^ (row & 7)) << 3)];
      }
      __builtin_amdgcn_s_setprio(1);
      #pragma unroll
      for (int jt = 0; jt < 8; ++jt)
        #pragma unroll
        for (int it = 0; it < 4; ++it)
          acc[jt][it] = __builtin_amdgcn_mfma_f32_16x16x32_bf16(bfr[jt], afr[it], acc[jt][it], 0, 0, 0);
      __builtin_amdgcn_s_setprio(0);
    }
  };

  // wait for own ch0 loads only (8 newest = ch1 still in flight), then barrier:
  // every wave has its ch0 landed => whole tile-0 in LDS.
  asm volatile("s_waitcnt vmcnt(8)" ::: "memory");
  __builtin_amdgcn_s_barrier();
  asm volatile("" ::: "memory");

  compute_chunk(As0, Bs0);

  asm volatile("s_waitcnt vmcnt(0)" ::: "memory");
  __builtin_amdgcn_s_barrier();
  asm volatile("" ::: "memory");

  compute_chunk(As1, Bs1);

  __syncthreads();   // all As/Bs reads done; Gs (aliases them) safe to write

  // single dump of all 64 rij. D[m=jk (quad*4+r)][n=ih (l15)]; b64 packs.
  #pragma unroll
  for (int jt = 0; jt < 8; ++jt)
    #pragma unroll
    for (int it = 0; it < 4; ++it) {
      const int rij = (wi * 2 + (it >> 1)) * 8 + wj * 4 + (jt >> 1);   // 0..63
      const int h = (it & 1) * 16 + l15;
      const int hk = h * 32 + (jt & 1) * 16 + quad * 4;
      const int g4 = hk >> 2;
      const int g4s = g4 ^ ((g4 >> 4) & 6) ^ ((rij & 7) << 1);
      __hip_bfloat162 lo = __float22bfloat162_rn(float2{acc[jt][it][0], acc[jt][it][1]});
      __hip_bfloat162 hi = __float22bfloat162_rn(float2{acc[jt][it][2], acc[jt][it][3]});
      union { __hip_bfloat162 h2[2]; uint2 u; } pk; pk.h2[0] = lo; pk.h2[1] = hi;
      *(uint2*)&Gs[rij * 1024 + (g4s << 2)] = pk.u;
    }
  __syncthreads();

  // single stage B: wave = (kq = wv>>1, ph = wv&1); M=64 (4 mt), N=32 (2 nt),
  // K = 256 hk (8 ks); W_t2 read exactly once per block.
  const int kq = wv >> 1, ph = wv & 1;
  f32x4 ob[4][2];
  #pragma unroll
  for (int mt = 0; mt < 4; ++mt)
    #pragma unroll
    for (int nt = 0; nt < 2; ++nt) ob[mt][nt] = fz;
  #pragma unroll 2
  for (int ks = 0; ks < 8; ++ks) {
    const int kb = kq * 32 + ks * 4 + quad;       // hk>>3
    const int g4e = kb * 2;
    short8 ga[4], wf[2];
    #pragma unroll
    for (int mt = 0; mt < 4; ++mt) {
      const int row = mt * 16 + l15;              // = rij
      const int go = (g4e ^ ((g4e >> 4) & 6) ^ ((row & 7) << 1)) << 2;
      ga[mt] = *(const short8*)&Gs[row * 1024 + go];
    }
    #pragma unroll
    for (int nt = 0; nt < 2; ++nt)
      wf[nt] = *(const short8*)&W_t[kb * 512 + (ph * 32 + nt * 16 + l15) * 8];
    __builtin_amdgcn_s_setprio(1);
    #pragma unroll
    for (int mt = 0; mt < 4; ++mt)
      #pragma unroll
      for (int nt = 0; nt < 2; ++nt)
        ob[mt][nt] = __builtin_amdgcn_mfma_f32_16x16x32_bf16(ga[mt], wf[nt], ob[mt][nt], 0, 0, 0);
    __builtin_amdgcn_s_setprio(0);
  }
  __syncthreads();   // all Gs reads done -> red may overwrite

  #pragma unroll
  for (int mt = 0; mt < 4; ++mt)
    #pragma unroll
    for (int nt = 0; nt < 2; ++nt)
      #pragma unroll
      for (int r = 0; r < 4; ++r) {
        const int rij = mt * 16 + quad * 4 + r;
        const int p = ph * 32 + nt * 16 + l15;
        red[(kq * 64 + rij) * 68 + p] = ob[mt][nt][r];
      }
  __syncthreads();

  // reduce 4 kq partials + bias + store: thread t -> (rij = t>>3, 8 p)
  {
    const int rij = tid >> 3, po = (tid & 7) * 8;
    f32x4 s0 = fz, s1 = fz;
    #pragma unroll
    for (int q = 0; q < 4; ++q) {
      s0 += *(const f32x4*)&red[(q * 64 + rij) * 68 + po];
      s1 += *(const f32x4*)&red[(q * 64 + rij) * 68 + po + 4];
    }
    const float4 bo0 = ((const float4*)bo)[(tid & 7) * 2];
    const float4 bo1 = ((const float4*)bo)[(tid & 7) * 2 + 1];
    const int iG = iT * 8 + (rij >> 3), jG = jT * 8 + (rij & 7);
    float* op = &out[(iG * NDIM + jG) * PDIM + po];
    float4 o0, o1;
    o0.x = s0[0] + bo0.x; o0.y = s0[1] + bo0.y; o0.z = s0[2] + bo0.z; o0.w = s0[3] + bo0.w;
    o1.x = s1[0] + bo1.x; o1.y = s1[1] + bo1.y; o1.z = s1[2] + bo1.z; o1.w = s1[3] + bo1.w;
    *(float4*)op = o0;
    *(float4*)(op + 4) = o1;
  }
}

extern "C" void kernel_launch(void* const* d_in, const int* in_sizes, int n_in,
                              void* d_out, int out_size, void* d_ws, size_t ws_size,
                              hipStream_t stream) {
  const float* msa   = (const float*)d_in[0];
  const float* mask  = (const float*)d_in[1];
  const float* gamma = (const float*)d_in[2];
  const float* beta  = (const float*)d_in[3];
  const float* Wa    = (const float*)d_in[4];
  const float* ba    = (const float*)d_in[5];
  const float* Wb    = (const float*)d_in[6];
  const float* bb    = (const float*)d_in[7];
  const float* Wo    = (const float*)d_in[8];
  const float* bo    = (const float*)d_in[9];

  char* ws = (char*)d_ws;
  u16* a_t = (u16*)ws;                       // 2 MB: [8192 ih][128 s] bf16 (pre-swizzled rows)
  u16* b_t = (u16*)(ws + (2u << 20));        // 2 MB: [8192 jk][128 s] bf16 (pre-swizzled rows)
  u16* W_t = (u16*)(ws + (4u << 20));        // 128 KB: [hk/8][p][hk%8] bf16

  static_cast<void>(hipFuncSetAttribute(
      reinterpret_cast<const void*>(&k_fused),
      hipFuncAttributeMaxDynamicSharedMemorySize, 131072));

  k_pre<<<dim3(1024), dim3(256), 0, stream>>>(msa, mask, gamma, beta,
                                              Wa, ba, Wb, bb, Wo, a_t, b_t, W_t);
  k_fused<<<dim3(32, 32), dim3(512), 131072, stream>>>(a_t, b_t, W_t, bo, (float*)d_out);
}

// Round 3
// 113.841 us; speedup vs baseline: 1.0277x; 1.0277x over previous
//
#include <hip/hip_runtime.h>
#include <hip/hip_bf16.h>
#include <stdint.h>

typedef unsigned short u16;
typedef __attribute__((ext_vector_type(8))) short short8;
typedef __attribute__((ext_vector_type(4))) float f32x4;

#define NDIM 256
#define SDIM 128
#define DDIM 64
#define HDIM 32
#define PDIM 64
#define EPS 1e-5f

__device__ __forceinline__ u16 f2bf(float f) {
  union { float f; uint32_t u; } v; v.f = f;
  uint32_t r = v.u + 0x7fffu + ((v.u >> 16) & 1u);   // RNE
  return (u16)(r >> 16);
}

// ---------------- K1: LN + dual projection via MFMA ----------------
// grid 1024: block = (n = bid>>2, sq = bid&3 -> 32 s-rows). 256 thr = 4 waves.
// a_t/b_t rows PRE-SWIZZLED: element s of row c at position
// (s&64)|(((s>>3)&7)^(c&7))<<3|(s&7). Epilogue goes through an LDS transpose
// so each thread issues ONE b128 global store.
__global__ __launch_bounds__(256, 4) void k_pre(
    const float* __restrict__ msa, const float* __restrict__ mask,
    const float* __restrict__ gamma, const float* __restrict__ beta,
    const float* __restrict__ Wa, const float* __restrict__ ba,
    const float* __restrict__ Wb, const float* __restrict__ bb,
    const float* __restrict__ Wo,
    u16* __restrict__ a_t, u16* __restrict__ b_t, u16* __restrict__ W_t)
{
  __shared__ u16 xs[32 * 64];        // [s][granule swizzled] 4KB X_norm bf16
  __shared__ u16 wt[64 * 64];        // [c][granule swizzled] 8KB W^T bf16
  __shared__ u16 oT[64 * 32];        // [c][s_local] 4KB output transpose
  __shared__ float psum[2][8][32];
  __shared__ float maskF[128];
  __shared__ float gbF[128];

  const int n = blockIdx.x >> 2, sq = blockIdx.x & 3;
  const int t = threadIdx.x, lane = t & 63, wv = t >> 6;
  const int l15 = lane & 15, quad = lane >> 4;

  if (t < 64) gbF[t] = gamma[t];
  else if (t < 128) gbF[t] = beta[t - 64];
  else maskF[t - 128] = mask[(t - 128) * NDIM + n];

  // LN partials: row sl (0..31), d-slice pt8 (8 floats); 8 thr share a row
  const int sl = t >> 3, pt8 = t & 7;
  float x[8];
  {
    const float* xr = msa + ((sq * 32 + sl) * NDIM + n) * DDIM + pt8 * 8;
    float sum = 0.f, sq2 = 0.f;
    #pragma unroll
    for (int i = 0; i < 2; ++i) {
      const float4 q = ((const float4*)xr)[i];
      x[4*i] = q.x; x[4*i+1] = q.y; x[4*i+2] = q.z; x[4*i+3] = q.w;
      sum += q.x + q.y + q.z + q.w;
      sq2 += q.x*q.x + q.y*q.y + q.z*q.z + q.w*q.w;
    }
    psum[0][pt8][sl] = sum;
    psum[1][pt8][sl] = sq2;
  }

  // W^T: col c = t&63, d-slice (t>>6)*16
  {
    const int c = t & 63, ds = t >> 6;
    const int c31 = c & 31;
    const float* Wsel = (c >> 5) ? Wb : Wa;
    float w[16];
    #pragma unroll
    for (int i = 0; i < 16; ++i) w[i] = Wsel[(ds * 16 + i) * HDIM + c31];
    #pragma unroll
    for (int jj = 0; jj < 2; ++jj) {
      short8 v;
      #pragma unroll
      for (int k = 0; k < 8; ++k) v[k] = (short)f2bf(w[jj * 8 + k]);
      *(short8*)&wt[c * 64 + (((ds * 2 + jj) ^ (c & 7)) << 3)] = v;
    }
  }
  __syncthreads();

  // finish LN
  {
    float s0 = 0.f, s1 = 0.f;
    #pragma unroll
    for (int q = 0; q < 8; ++q) { s0 += psum[0][q][sl]; s1 += psum[1][q][sl]; }
    const float mu = s0 * (1.f / 64.f);
    const float var = s1 * (1.f / 64.f) - mu * mu;
    const float rs = rsqrtf(var + EPS);
    short8 v;
    #pragma unroll
    for (int k = 0; k < 8; ++k) {
      const int d = pt8 * 8 + k;
      v[k] = (short)f2bf((x[k] - mu) * rs * gbF[d] + gbF[64 + d]);
    }
    *(short8*)&xs[sl * 64 + ((pt8 ^ (sl & 7)) << 3)] = v;
  }
  float m2 = maskF[lane] + maskF[64 + lane];
  #pragma unroll
  for (int m = 32; m; m >>= 1) m2 += __shfl_xor(m2, m, 64);
  const float dinv = 1.f / fmaxf(m2, 1.f);
  __syncthreads();

  // projection: D[m=c][n=s], wave wv = c-tile [wv*16,+16); s covers 32 (2 nt)
  const f32x4 fz = {0.f, 0.f, 0.f, 0.f};
  f32x4 acc[2] = {fz, fz};
  short8 af[2];
  #pragma unroll
  for (int ks = 0; ks < 2; ++ks)
    af[ks] = *(const short8*)&wt[(wv * 16 + l15) * 64 + (((ks * 4 + quad) ^ (l15 & 7)) << 3)];
  #pragma unroll
  for (int nt = 0; nt < 2; ++nt)
    #pragma unroll
    for (int ks = 0; ks < 2; ++ks) {
      const short8 bf = *(const short8*)&xs[(nt * 16 + l15) * 64 + (((ks * 4 + quad) ^ (l15 & 7)) << 3)];
      acc[nt] = __builtin_amdgcn_mfma_f32_16x16x32_bf16(af[ks], bf, acc[nt], 0, 0, 0);
    }

  // epilogue -> LDS transpose
  const float* bsel = (wv < 2) ? ba : bb;
  float bias_r[4];
  #pragma unroll
  for (int r = 0; r < 4; ++r) bias_r[r] = bsel[(wv & 1) * 16 + quad * 4 + r];
  #pragma unroll
  for (int nt = 0; nt < 2; ++nt) {
    const int s = sq * 32 + nt * 16 + l15;
    const int slcl = nt * 16 + l15;
    const float mval = maskF[s];
    const float scale = (wv < 2) ? mval * dinv : mval;
    #pragma unroll
    for (int r = 0; r < 4; ++r) {
      const int c31 = (wv & 1) * 16 + quad * 4 + r;
      const int c = ((wv < 2) ? 0 : 32) + c31;
      oT[c * 32 + slcl] = f2bf((acc[nt][r] + bias_r[r]) * scale);
    }
  }
  __syncthreads();

  // one b128 store per thread: thread -> (c = t>>2, granule gi = t&3)
  {
    const int c = t >> 2, gi = t & 3;
    const int c31 = c & 31;
    const int s0 = sq * 32 + gi * 8;
    u16* dst = ((c < 32) ? a_t : b_t) + n * 4096 + c31 * 128
             + (s0 & 64) + ((((s0 >> 3) & 7) ^ (c31 & 7)) << 3);
    *(short8*)dst = *(const short8*)&oT[c * 32 + gi * 8];
  }

  // W_t2[hk>>3][p][hk&7] = bf16(Wo[hk][p])
  if (blockIdx.x < 256) {
    const int f = blockIdx.x * 256 + t;        // f = hk*64 + p
    const int p = f & 63, hk = f >> 6;
    W_t[(hk >> 3) * 512 + p * 8 + (hk & 7)] = f2bf(Wo[f]);
  }
}

// ---------------- K2: fused outer-product GEMM + Wo contraction ----------------
// RESTRUCTURED for 2 blocks/CU: tile is now 256 ih x 128 jk (8 i x 4 j = 32 rij),
// grid (64 jT, 32 iT), 512 thr = 8 waves (wi 0..3 x wj 0..1, wave tile 64x64,
// acc[4][4] = 64 VGPR). 80 KB dynamic LDS -> exactly 2 blocks/CU (160 KB), so
// the 7 phase barriers of one block are filled by the co-resident block
// (previous 128KB/1-block structure exposed them; R1's staging overlap was
// neutral because barriers, not loads, were the bubble). launch_bounds(512,4)
// caps VGPR at 128. A-chunk-1 staged up front (counted vmcnt(4)); only the
// 16 KB B-chunk-1 load is exposed. Gs[32][1024] (64KB) and red[4][32][68]
// (34.8KB) alias the staging buffers.
__global__ __launch_bounds__(512, 4) void k_fused(
    const u16* __restrict__ a_t, const u16* __restrict__ b_t,
    const u16* __restrict__ W_t, const float* __restrict__ bo,
    float* __restrict__ out)
{
  extern __shared__ char smem[];
  u16* As0 = (u16*)smem;                  // [256 ih][64 k] chunk0, 32KB
  u16* BsS = (u16*)(smem + 32768);        // [128 jk][64 k] (chunk0 then chunk1), 16KB
  u16* As1 = (u16*)(smem + 49152);        // [256 ih][64 k] chunk1, 32KB  (total 80KB)
  u16* Gs  = (u16*)smem;                  // [32 rij][1024 hk] swizzled, 64KB (alias)
  float* red = (float*)smem;              // [4 kq][32 rij][68] f32, 34.8KB (alias)

  const int tid = threadIdx.x, lane = tid & 63, wv = tid >> 6;
  const int l15 = lane & 15, quad = lane >> 4;
  const int wi = wv >> 1, wj = wv & 1;
  const int jT = blockIdx.x, iT = blockIdx.y;

  const u16* gA = a_t + iT * 256 * SDIM;
  const u16* gB = b_t + jT * 128 * SDIM;

  const f32x4 fz = {0.f, 0.f, 0.f, 0.f};
  f32x4 acc[4][4];                   // [jt][it]
  #pragma unroll
  for (int jt = 0; jt < 4; ++jt)
    #pragma unroll
    for (int it = 0; it < 4; ++it) acc[jt][it] = fz;

  const int sub8 = lane >> 3, g16 = lane & 7;

  // ---- issue staging: As ch0 (4), Bs ch0 (2), As ch1 (4) = 10 per wave ----
  #pragma unroll
  for (int i = 0; i < 4; ++i) {
    const int rbase = wv * 32 + i * 8;
    __builtin_amdgcn_global_load_lds(
        (const __attribute__((address_space(1))) void*)&gA[(rbase + sub8) * SDIM + g16 * 8],
        (__attribute__((address_space(3))) void*)&As0[rbase * 64], 16, 0, 0);
  }
  #pragma unroll
  for (int i = 0; i < 2; ++i) {
    const int rbase = wv * 16 + i * 8;
    __builtin_amdgcn_global_load_lds(
        (const __attribute__((address_space(1))) void*)&gB[(rbase + sub8) * SDIM + g16 * 8],
        (__attribute__((address_space(3))) void*)&BsS[rbase * 64], 16, 0, 0);
  }
  #pragma unroll
  for (int i = 0; i < 4; ++i) {
    const int rbase = wv * 32 + i * 8;
    __builtin_amdgcn_global_load_lds(
        (const __attribute__((address_space(1))) void*)&gA[(rbase + sub8) * SDIM + 64 + g16 * 8],
        (__attribute__((address_space(3))) void*)&As1[rbase * 64], 16, 0, 0);
  }

  auto compute_chunk = [&](const u16* __restrict__ Asb, const u16* __restrict__ Bsb) {
    #pragma unroll
    for (int ks = 0; ks < 2; ++ks) {
      const int g = ks * 4 + quad;
      short8 afr[4], bfr[4];
      #pragma unroll
      for (int it = 0; it < 4; ++it) {
        const int row = wi * 64 + it * 16 + l15;
        afr[it] = *(const short8*)&Asb[row * 64 + ((g ^ (row & 7)) << 3)];
      }
      #pragma unroll
      for (int jt = 0; jt < 4; ++jt) {
        const int row = wj * 64 + jt * 16 + l15;
        bfr[jt] = *(const short8*)&Bsb[row * 64 + ((g ^ (row & 7)) << 3)];
      }
      __builtin_amdgcn_s_setprio(1);
      #pragma unroll
      for (int jt = 0; jt < 4; ++jt)
        #pragma unroll
        for (int it = 0; it < 4; ++it)
          acc[jt][it] = __builtin_amdgcn_mfma_f32_16x16x32_bf16(bfr[jt], afr[it], acc[jt][it], 0, 0, 0);
      __builtin_amdgcn_s_setprio(0);
    }
  };

  // ch0 ready when 6 oldest landed (4 newest = As1 still in flight)
  asm volatile("s_waitcnt vmcnt(4)" ::: "memory");
  __builtin_amdgcn_s_barrier();
  asm volatile("" ::: "memory");

  compute_chunk(As0, BsS);

  __builtin_amdgcn_s_barrier();            // all Bs ch0 reads done
  asm volatile("" ::: "memory");
  #pragma unroll
  for (int i = 0; i < 2; ++i) {            // Bs ch1 into same slot
    const int rbase = wv * 16 + i * 8;
    __builtin_amdgcn_global_load_lds(
        (const __attribute__((address_space(1))) void*)&gB[(rbase + sub8) * SDIM + 64 + g16 * 8],
        (__attribute__((address_space(3))) void*)&BsS[rbase * 64], 16, 0, 0);
  }
  asm volatile("s_waitcnt vmcnt(0)" ::: "memory");
  __builtin_amdgcn_s_barrier();
  asm volatile("" ::: "memory");

  compute_chunk(As1, BsS);

  __syncthreads();   // all As/Bs reads done; Gs (aliases them) safe to write

  // dump all 32 rij. D[m=jk (quad*4+r)][n=ih (l15)]; one b64 per acc tile.
  #pragma unroll
  for (int jt = 0; jt < 4; ++jt)
    #pragma unroll
    for (int it = 0; it < 4; ++it) {
      const int rij = (wi * 2 + (it >> 1)) * 4 + wj * 2 + (jt >> 1);   // 0..31
      const int h = (it & 1) * 16 + l15;
      const int hk = h * 32 + (jt & 1) * 16 + quad * 4;
      const int g4 = hk >> 2;
      const int g4s = g4 ^ ((g4 >> 4) & 6) ^ ((rij & 7) << 1);
      __hip_bfloat162 lo = __float22bfloat162_rn(float2{acc[jt][it][0], acc[jt][it][1]});
      __hip_bfloat162 hi = __float22bfloat162_rn(float2{acc[jt][it][2], acc[jt][it][3]});
      union { __hip_bfloat162 h2[2]; uint2 u; } pk; pk.h2[0] = lo; pk.h2[1] = hi;
      *(uint2*)&Gs[rij * 1024 + (g4s << 2)] = pk.u;
    }
  __syncthreads();

  // stage B: wave = (kq = wv>>1, ph = wv&1); M=32 rij (2 mt), N=32 p (2 nt),
  // K = 256 hk per kq (8 ks); W_t read exactly once per block.
  const int kq = wv >> 1, ph = wv & 1;
  f32x4 ob[2][2];
  #pragma unroll
  for (int mt = 0; mt < 2; ++mt)
    #pragma unroll
    for (int nt = 0; nt < 2; ++nt) ob[mt][nt] = fz;
  #pragma unroll 2
  for (int ks = 0; ks < 8; ++ks) {
    const int kb = kq * 32 + ks * 4 + quad;       // hk>>3
    short8 wf[2], ga[2];
    #pragma unroll
    for (int nt = 0; nt < 2; ++nt)
      wf[nt] = *(const short8*)&W_t[kb * 512 + (ph * 32 + nt * 16 + l15) * 8];
    const int g4e = kb * 2;
    #pragma unroll
    for (int mt = 0; mt < 2; ++mt) {
      const int row = mt * 16 + l15;              // = rij
      const int go = (g4e ^ ((g4e >> 4) & 6) ^ ((row & 7) << 1)) << 2;
      ga[mt] = *(const short8*)&Gs[row * 1024 + go];
    }
    __builtin_amdgcn_s_setprio(1);
    #pragma unroll
    for (int mt = 0; mt < 2; ++mt)
      #pragma unroll
      for (int nt = 0; nt < 2; ++nt)
        ob[mt][nt] = __builtin_amdgcn_mfma_f32_16x16x32_bf16(ga[mt], wf[nt], ob[mt][nt], 0, 0, 0);
    __builtin_amdgcn_s_setprio(0);
  }
  __syncthreads();   // all Gs reads done -> red may overwrite

  #pragma unroll
  for (int mt = 0; mt < 2; ++mt)
    #pragma unroll
    for (int nt = 0; nt < 2; ++nt)
      #pragma unroll
      for (int r = 0; r < 4; ++r) {
        const int rij = mt * 16 + quad * 4 + r;
        const int p = ph * 32 + nt * 16 + l15;
        red[(kq * 32 + rij) * 68 + p] = ob[mt][nt][r];
      }
  __syncthreads();

  // reduce 4 kq partials + bias + store: thread t -> (rij = t>>4, 4 p)
  {
    const int rij = tid >> 4, po = (tid & 15) * 4;
    f32x4 s0 = fz;
    #pragma unroll
    for (int q = 0; q < 4; ++q)
      s0 += *(const f32x4*)&red[(q * 32 + rij) * 68 + po];
    const float4 bo0 = ((const float4*)bo)[tid & 15];
    const int iG = iT * 8 + (rij >> 2), jG = jT * 4 + (rij & 3);
    float* op = &out[(iG * NDIM + jG) * PDIM + po];
    float4 o0;
    o0.x = s0[0] + bo0.x; o0.y = s0[1] + bo0.y; o0.z = s0[2] + bo0.z; o0.w = s0[3] + bo0.w;
    *(float4*)op = o0;
  }
}

extern "C" void kernel_launch(void* const* d_in, const int* in_sizes, int n_in,
                              void* d_out, int out_size, void* d_ws, size_t ws_size,
                              hipStream_t stream) {
  const float* msa   = (const float*)d_in[0];
  const float* mask  = (const float*)d_in[1];
  const float* gamma = (const float*)d_in[2];
  const float* beta  = (const float*)d_in[3];
  const float* Wa    = (const float*)d_in[4];
  const float* ba    = (const float*)d_in[5];
  const float* Wb    = (const float*)d_in[6];
  const float* bb    = (const float*)d_in[7];
  const float* Wo    = (const float*)d_in[8];
  const float* bo    = (const float*)d_in[9];

  char* ws = (char*)d_ws;
  u16* a_t = (u16*)ws;                       // 2 MB: [8192 ih][128 s] bf16 (pre-swizzled rows)
  u16* b_t = (u16*)(ws + (2u << 20));        // 2 MB: [8192 jk][128 s] bf16 (pre-swizzled rows)
  u16* W_t = (u16*)(ws + (4u << 20));        // 128 KB: [hk/8][p][hk%8] bf16

  static_cast<void>(hipFuncSetAttribute(
      reinterpret_cast<const void*>(&k_fused),
      hipFuncAttributeMaxDynamicSharedMemorySize, 81920));

  k_pre<<<dim3(1024), dim3(256), 0, stream>>>(msa, mask, gamma, beta,
                                              Wa, ba, Wb, bb, Wo, a_t, b_t, W_t);
  k_fused<<<dim3(64, 32), dim3(512), 81920, stream>>>(a_t, b_t, W_t, bo, (float*)d_out);
}